// Round 5
// baseline (213.285 us; speedup 1.0000x reference)
//
#include <hip/hip_runtime.h>
#include <math.h>

#define BN_EPS 1e-5f

typedef __attribute__((ext_vector_type(8))) short bf16x8;
typedef __attribute__((ext_vector_type(4))) float f32x4;

__device__ inline unsigned f2bf(float f) {
  union { float f; unsigned u; } v; v.f = f;
  unsigned r = v.u + 0x7FFF + ((v.u >> 16) & 1);   // round-nearest-even
  return r >> 16;
}

// add-only bf16x8 unpack-accumulate (norm folded into features)
__device__ inline void acc8n(float* a, uint4 v) {
  a[0] += __uint_as_float(v.x << 16);
  a[1] += __uint_as_float(v.x & 0xffff0000u);
  a[2] += __uint_as_float(v.y << 16);
  a[3] += __uint_as_float(v.y & 0xffff0000u);
  a[4] += __uint_as_float(v.z << 16);
  a[5] += __uint_as_float(v.z & 0xffff0000u);
  a[6] += __uint_as_float(v.w << 16);
  a[7] += __uint_as_float(v.w & 0xffff0000u);
}

__device__ inline void acc4n(float* a, uint2 v) {
  a[0] += __uint_as_float(v.x << 16);
  a[1] += __uint_as_float(v.x & 0xffff0000u);
  a[2] += __uint_as_float(v.y << 16);
  a[3] += __uint_as_float(v.y & 0xffff0000u);
}

// ---------------- zero ----------------

__global__ void k_zero(uint4* __restrict__ p, int n16) {
  int i = blockIdx.x * blockDim.x + threadIdx.x;
  if (i < n16) p[i] = make_uint4(0, 0, 0, 0);
}

// ---------------- CSR build ----------------

__global__ void k_count(const int* __restrict__ dst, int* __restrict__ deg,
                        int* __restrict__ posw, int E) {
  int e = blockIdx.x * blockDim.x + threadIdx.x;
  if (e < E) posw[e] = atomicAdd(&deg[dst[e]], 1);
}

__global__ void k_scan1(const int* __restrict__ deg, int* __restrict__ rowstart,
                        int* __restrict__ chunksum, int n) {
  __shared__ int s[1024];
  int i = blockIdx.x * 1024 + threadIdx.x;
  int v = (i < n) ? deg[i] : 0;
  s[threadIdx.x] = v;
  __syncthreads();
  for (int off = 1; off < 1024; off <<= 1) {
    int t = (threadIdx.x >= off) ? s[threadIdx.x - off] : 0;
    __syncthreads();
    s[threadIdx.x] += t;
    __syncthreads();
  }
  if (i < n) rowstart[i] = s[threadIdx.x] - v;   // exclusive within chunk
  if (threadIdx.x == 1023) chunksum[blockIdx.x] = s[1023];
}

__global__ void k_scan2(int* __restrict__ chunksum, int nchunks) {
  if (threadIdx.x == 0 && blockIdx.x == 0) {
    int run = 0;
    for (int i = 0; i < nchunks; i++) { int v = chunksum[i]; chunksum[i] = run; run += v; }
  }
}

__global__ void k_scan3(int* __restrict__ rowstart, const int* __restrict__ chunksum,
                        const int* __restrict__ deg, float* __restrict__ dis,
                        int n, int E) {
  int i = blockIdx.x * blockDim.x + threadIdx.x;
  if (i < n) {
    rowstart[i] += chunksum[i >> 10];
    dis[i] = rsqrtf((float)(deg[i] + 1));   // +1 self loop
  }
  if (i == 0) rowstart[n] = E;
}

// ------------- prep: BN fold (incl. bias) + weight transpose/bf16 + b3 pad -------------

__global__ void k_prep(const float* __restrict__ W1, const float* __restrict__ W2,
                       const float* __restrict__ W3,
                       const float* __restrict__ g1, const float* __restrict__ be1,
                       const float* __restrict__ m1, const float* __restrict__ v1,
                       const float* __restrict__ g2, const float* __restrict__ be2,
                       const float* __restrict__ m2, const float* __restrict__ v2,
                       const float* __restrict__ b1, const float* __restrict__ b2,
                       const float* __restrict__ b3,
                       ushort* __restrict__ WT1, ushort* __restrict__ WT2,
                       ushort* __restrict__ WT3,
                       float* __restrict__ sc1, float* __restrict__ sh1,
                       float* __restrict__ sc2, float* __restrict__ sh2,
                       float* __restrict__ b3pad) {
  int k = blockIdx.x;      // 128
  int n = threadIdx.x;     // 128
  WT1[n * 128 + k] = (ushort)f2bf(W1[k * 128 + n]);
  WT2[n * 128 + k] = (ushort)f2bf(W2[k * 128 + n]);
  WT3[n * 128 + k] = (n < 40) ? (ushort)f2bf(W3[k * 40 + n]) : (ushort)0;
  if (k == 0) {
    float s1 = g1[n] * rsqrtf(v1[n] + BN_EPS);
    sc1[n] = s1; sh1[n] = be1[n] + (b1[n] - m1[n]) * s1;    // bias folded in
    float s2 = g2[n] * rsqrtf(v2[n] + BN_EPS);
    sc2[n] = s2; sh2[n] = be2[n] + (b2[n] - m2[n]) * s2;
  } else if (k == 1 && n < 64) {
    b3pad[n] = (n < 40) ? b3[n] : 0.f;
  }
}

// ---- MFMA GEMM: C[r][c] = dis[r] * (A[r][:] @ W[:][c]), bf16 out.  Optional fused
// ---- CSR-fill role for blocks >= gemmBlocks (layer 1: fill hides under GEMM).

template <bool F32A, bool FILL>
__global__ __launch_bounds__(256) void k_gemm_bf16(const void* __restrict__ Ap,
                                                   const ushort* __restrict__ WT,
                                                   ushort* __restrict__ C,
                                                   const float* __restrict__ dis,
                                                   int nrows, int NC, int gemmBlocks,
                                                   const int* __restrict__ ei,
                                                   const int* __restrict__ rowstart,
                                                   const int* __restrict__ posw,
                                                   unsigned* __restrict__ slot, int E) {
  if (FILL && (int)blockIdx.x >= gemmBlocks) {
    int e = ((int)blockIdx.x - gemmBlocks) * 256 + threadIdx.x;
    if (e < E) slot[rowstart[ei[E + e]] + posw[e]] = (unsigned)ei[e];
    return;
  }
  __shared__ ushort As[128][80];
  __shared__ ushort Bs[128][80];
  const int tid  = threadIdx.x;
  const int lane = tid & 63;
  const int wid  = tid >> 6;
  const int wr   = wid >> 1, wc = wid & 1;
  const int row0 = blockIdx.x * 128;
  f32x4 acc[4][4] = {};

  const int mrow = lane & 15;
  const int kg   = (lane >> 4) * 8;

  for (int k0 = 0; k0 < 128; k0 += 64) {
    __syncthreads();
    for (int i = tid; i < 1024; i += 256) {        // A tile: 128 rows x 64 bf16
      int r = i >> 3, c = (i & 7) * 8;
      uint4 w = make_uint4(0, 0, 0, 0);
      if (row0 + r < nrows) {
        if (F32A) {
          const float* A = (const float*)Ap;
          float4 v0 = *(const float4*)(A + (size_t)(row0 + r) * 128 + k0 + c);
          float4 v1 = *(const float4*)(A + (size_t)(row0 + r) * 128 + k0 + c + 4);
          w.x = f2bf(v0.x) | (f2bf(v0.y) << 16);
          w.y = f2bf(v0.z) | (f2bf(v0.w) << 16);
          w.z = f2bf(v1.x) | (f2bf(v1.y) << 16);
          w.w = f2bf(v1.z) | (f2bf(v1.w) << 16);
        } else {
          const ushort* A = (const ushort*)Ap;
          w = *(const uint4*)(A + (size_t)(row0 + r) * 128 + k0 + c);
        }
      }
      *(uint4*)(&As[r][c]) = w;
    }
    for (int i = tid; i < 1024; i += 256) {        // B tile: 128 n-rows x 64 bf16 (k)
      int r = i >> 3, c = (i & 7) * 8;
      *(uint4*)(&Bs[r][c]) = *(const uint4*)(WT + r * 128 + k0 + c);
    }
    __syncthreads();

#pragma unroll
    for (int ks = 0; ks < 2; ks++) {
      bf16x8 a[4], b[4];
#pragma unroll
      for (int f = 0; f < 4; f++) {
        a[f] = *(const bf16x8*)(&As[wr * 64 + f * 16 + mrow][ks * 32 + kg]);
        b[f] = *(const bf16x8*)(&Bs[wc * 64 + f * 16 + mrow][ks * 32 + kg]);
      }
#pragma unroll
      for (int fm = 0; fm < 4; fm++)
#pragma unroll
        for (int fn = 0; fn < 4; fn++)
          acc[fm][fn] = __builtin_amdgcn_mfma_f32_16x16x32_bf16(a[fm], b[fn], acc[fm][fn], 0, 0, 0);
    }
  }

  // C/D layout: col = lane&15, row = (lane>>4)*4 + reg
  const int rl = (lane >> 4) * 4;
  const int cl = lane & 15;
#pragma unroll
  for (int fm = 0; fm < 4; fm++) {
#pragma unroll
    for (int r = 0; r < 4; r++) {
      int row = row0 + wr * 64 + fm * 16 + rl + r;
      if (row >= nrows) continue;
      float dn = dis[row];
#pragma unroll
      for (int fn = 0; fn < 4; fn++) {
        int col = wc * 64 + fn * 16 + cl;
        if (col < NC) C[(size_t)row * NC + col] = (ushort)f2bf(acc[fm][fn][r] * dn);
      }
    }
  }
}

// ---- Aggregation (D=128): out = relu(sc*(dis[n]*(Σ h'[src] + h'[n])) + sh), bf16 ------
// Wave = 4 edge-groups x 16 lanes; lane gathers 8 channels (16B). 2x unrolled gathers.

__global__ __launch_bounds__(256) void k_agg128b(const ushort* __restrict__ h,
                          const int* __restrict__ rowstart,
                          const unsigned* __restrict__ slot,
                          const float* __restrict__ dis,
                          const float* __restrict__ bnsc,
                          const float* __restrict__ bnsh,
                          ushort* __restrict__ out, int nnodes) {
  int node = blockIdx.x * 4 + threadIdx.y;
  if (node >= nnodes) return;
  int lane = threadIdx.x;
  int eg = lane >> 4, cl = lane & 15, c0 = cl * 8;
  int s = rowstart[node], e = rowstart[node + 1];
  int deg = e - s;
  unsigned mys = 0;
  if (lane < deg) mys = slot[s + lane];
  float a[8] = {0.f, 0.f, 0.f, 0.f, 0.f, 0.f, 0.f, 0.f};
  int nb = deg < 64 ? deg : 64;
  int i = eg;
  for (; i + 4 < nb; i += 8) {
    int s0 = __shfl((int)mys, i);
    int s1 = __shfl((int)mys, i + 4);
    uint4 h0 = *(const uint4*)(h + (size_t)s0 * 128 + c0);
    uint4 h1 = *(const uint4*)(h + (size_t)s1 * 128 + c0);
    acc8n(a, h0);
    acc8n(a, h1);
  }
  if (i < nb) {
    int s0 = __shfl((int)mys, i);
    uint4 h0 = *(const uint4*)(h + (size_t)s0 * 128 + c0);
    acc8n(a, h0);
  }
  for (int j = s + 64 + eg; j < e; j += 4) {     // rare tail (deg > 64)
    uint4 h0 = *(const uint4*)(h + (size_t)slot[j] * 128 + c0);
    acc8n(a, h0);
  }
#pragma unroll
  for (int j = 0; j < 8; j++) {
    a[j] += __shfl_xor(a[j], 16);
    a[j] += __shfl_xor(a[j], 32);
  }
  if (eg == 0) {
    uint4 hv = *(const uint4*)(h + (size_t)node * 128 + c0);
    acc8n(a, hv);                                 // self loop
    float dn = dis[node];
    float4 sc0 = *(const float4*)(bnsc + c0), sc1 = *(const float4*)(bnsc + c0 + 4);
    float4 sh0 = *(const float4*)(bnsh + c0), sh1 = *(const float4*)(bnsh + c0 + 4);
    float o0 = fmaxf(fmaf(a[0] * dn, sc0.x, sh0.x), 0.f);
    float o1 = fmaxf(fmaf(a[1] * dn, sc0.y, sh0.y), 0.f);
    float o2 = fmaxf(fmaf(a[2] * dn, sc0.z, sh0.z), 0.f);
    float o3 = fmaxf(fmaf(a[3] * dn, sc0.w, sh0.w), 0.f);
    float o4 = fmaxf(fmaf(a[4] * dn, sc1.x, sh1.x), 0.f);
    float o5 = fmaxf(fmaf(a[5] * dn, sc1.y, sh1.y), 0.f);
    float o6 = fmaxf(fmaf(a[6] * dn, sc1.z, sh1.z), 0.f);
    float o7 = fmaxf(fmaf(a[7] * dn, sc1.w, sh1.w), 0.f);
    uint4 w;
    w.x = f2bf(o0) | (f2bf(o1) << 16);
    w.y = f2bf(o2) | (f2bf(o3) << 16);
    w.z = f2bf(o4) | (f2bf(o5) << 16);
    w.w = f2bf(o6) | (f2bf(o7) << 16);
    *(uint4*)(out + (size_t)node * 128 + c0) = w;
  }
}

// -------- Aggregation (64-padded layer-3) + log_softmax (fp32 out, 40 ch) --------------

__global__ __launch_bounds__(256) void k_agg64_lsm(const ushort* __restrict__ h,
                            const int* __restrict__ rowstart,
                            const unsigned* __restrict__ slot,
                            const float* __restrict__ dis,
                            const float* __restrict__ b3pad,
                            float* __restrict__ out, int nnodes) {
  int node = blockIdx.x * 4 + threadIdx.y;
  if (node >= nnodes) return;
  int lane = threadIdx.x;
  int eg = lane >> 4, cl = lane & 15, c0 = cl * 4;
  int s = rowstart[node], e = rowstart[node + 1];
  int deg = e - s;
  unsigned mys = 0;
  if (lane < deg) mys = slot[s + lane];
  float a[4] = {0.f, 0.f, 0.f, 0.f};
  int nb = deg < 64 ? deg : 64;
  int i = eg;
  for (; i + 4 < nb; i += 8) {
    int s0 = __shfl((int)mys, i);
    int s1 = __shfl((int)mys, i + 4);
    uint2 h0 = *(const uint2*)(h + (size_t)s0 * 64 + c0);
    uint2 h1 = *(const uint2*)(h + (size_t)s1 * 64 + c0);
    acc4n(a, h0);
    acc4n(a, h1);
  }
  if (i < nb) {
    int s0 = __shfl((int)mys, i);
    uint2 h0 = *(const uint2*)(h + (size_t)s0 * 64 + c0);
    acc4n(a, h0);
  }
  for (int j = s + 64 + eg; j < e; j += 4) {
    uint2 h0 = *(const uint2*)(h + (size_t)slot[j] * 64 + c0);
    acc4n(a, h0);
  }
#pragma unroll
  for (int j = 0; j < 4; j++) {
    a[j] += __shfl_xor(a[j], 16);
    a[j] += __shfl_xor(a[j], 32);
  }
  // self loop + dis scale + bias (identical across edge groups)
  {
    uint2 hv = *(const uint2*)(h + (size_t)node * 64 + c0);
    acc4n(a, hv);
    float dn = dis[node];
    float4 bb = *(const float4*)(b3pad + c0);
    a[0] = fmaf(a[0], dn, bb.x);
    a[1] = fmaf(a[1], dn, bb.y);
    a[2] = fmaf(a[2], dn, bb.z);
    a[3] = fmaf(a[3], dn, bb.w);
  }
  bool valid = cl < 10;   // channels 4*cl..4*cl+3 < 40
  float m = valid ? fmaxf(fmaxf(a[0], a[1]), fmaxf(a[2], a[3])) : -INFINITY;
#pragma unroll
  for (int off = 1; off < 16; off <<= 1) m = fmaxf(m, __shfl_xor(m, off));
  float ss = valid ? (expf(a[0] - m) + expf(a[1] - m) + expf(a[2] - m) + expf(a[3] - m)) : 0.f;
#pragma unroll
  for (int off = 1; off < 16; off <<= 1) ss += __shfl_xor(ss, off);
  float lse = m + logf(ss);
  if (eg == 0 && valid) {
    *(float4*)(out + (size_t)node * 40 + c0) =
        make_float4(a[0] - lse, a[1] - lse, a[2] - lse, a[3] - lse);
  }
}

// ---------------- launch ----------------

extern "C" void kernel_launch(void* const* d_in, const int* in_sizes, int n_in,
                              void* d_out, int out_size, void* d_ws, size_t ws_size,
                              hipStream_t stream) {
  const float* x   = (const float*)d_in[0];
  const int*   ei  = (const int*)d_in[1];
  const float* W1  = (const float*)d_in[2];
  const float* b1  = (const float*)d_in[3];
  const float* W2  = (const float*)d_in[4];
  const float* b2  = (const float*)d_in[5];
  const float* W3  = (const float*)d_in[6];
  const float* b3  = (const float*)d_in[7];
  const float* g1  = (const float*)d_in[8];
  const float* be1 = (const float*)d_in[9];
  const float* m1  = (const float*)d_in[10];
  const float* v1  = (const float*)d_in[11];
  const float* g2  = (const float*)d_in[12];
  const float* be2 = (const float*)d_in[13];
  const float* m2  = (const float*)d_in[14];
  const float* v2  = (const float*)d_in[15];

  const int N   = in_sizes[0] / 128;
  const int E   = in_sizes[1] / 2;

  float* outp = (float*)d_out;

  char* ws = (char*)d_ws;
  size_t off = 0;
  auto alloc = [&](size_t bytes) -> char* {
    char* p = ws + off;
    off = (off + bytes + 255) & ~(size_t)255;
    return p;
  };
  int*      deg      = (int*)alloc((size_t)N * 4);
  int*      posw     = (int*)alloc((size_t)E * 4);
  int*      rowstart = (int*)alloc((size_t)(N + 1) * 4);
  int*      chunksum = (int*)alloc(256 * 4);
  float*    dis      = (float*)alloc((size_t)N * 4);
  unsigned* slot     = (unsigned*)alloc((size_t)E * 4);
  float*    sc1      = (float*)alloc(128 * 4);
  float*    sh1      = (float*)alloc(128 * 4);
  float*    sc2      = (float*)alloc(128 * 4);
  float*    sh2      = (float*)alloc(128 * 4);
  float*    b3pad    = (float*)alloc(64 * 4);
  ushort*   WT1      = (ushort*)alloc(128 * 128 * 2);
  ushort*   WT2      = (ushort*)alloc(128 * 128 * 2);
  ushort*   WT3      = (ushort*)alloc(128 * 128 * 2);
  ushort*   bufA     = (ushort*)alloc((size_t)N * 128 * 2);
  ushort*   bufB     = (ushort*)alloc((size_t)N * 128 * 2);
  ushort*   bufC     = (ushort*)alloc((size_t)N * 64 * 2);
  (void)ws_size;

  const int T = 256;
  const int chunks = (N + 1023) / 1024;

  k_zero<<<(((N + 3) / 4) + T - 1) / T, T, 0, stream>>>((uint4*)deg, (N + 3) / 4);
  k_count<<<(E + T - 1) / T, T, 0, stream>>>(ei + E, deg, posw, E);
  k_scan1<<<chunks, 1024, 0, stream>>>(deg, rowstart, chunksum, N);
  k_scan2<<<1, 64, 0, stream>>>(chunksum, chunks);
  k_scan3<<<(N + T - 1) / T, T, 0, stream>>>(rowstart, chunksum, deg, dis, N, E);
  k_prep<<<128, 128, 0, stream>>>(W1, W2, W3, g1, be1, m1, v1, g2, be2, m2, v2,
                                  b1, b2, b3, WT1, WT2, WT3, sc1, sh1, sc2, sh2, b3pad);

  dim3 aggGrid((N + 3) / 4), aggBlk(64, 4);
  const int gBlocks = (N + 127) / 128;
  const int fBlocks = (E + 255) / 256;

  // Layer 1: GEMM (fp32 in, dis-scaled bf16 out) with CSR fill fused in extra blocks
  k_gemm_bf16<true, true><<<gBlocks + fBlocks, 256, 0, stream>>>(
      x, WT1, bufB, dis, N, 128, gBlocks, ei, rowstart, posw, slot, E);
  k_agg128b<<<aggGrid, aggBlk, 0, stream>>>(bufB, rowstart, slot, dis, sc1, sh1, bufA, N);

  // Layer 2
  k_gemm_bf16<false, false><<<gBlocks, 256, 0, stream>>>(
      bufA, WT2, bufB, dis, N, 128, gBlocks, nullptr, nullptr, nullptr, nullptr, 0);
  k_agg128b<<<aggGrid, aggBlk, 0, stream>>>(bufB, rowstart, slot, dis, sc2, sh2, bufA, N);

  // Layer 3 (64-padded) + log_softmax
  k_gemm_bf16<false, false><<<gBlocks, 256, 0, stream>>>(
      bufA, WT3, bufC, dis, N, 64, gBlocks, nullptr, nullptr, nullptr, nullptr, 0);
  k_agg64_lsm<<<aggGrid, aggBlk, 0, stream>>>(bufC, rowstart, slot, dis, b3pad, outp, N);
}

// Round 6
// 203.331 us; speedup vs baseline: 1.0490x; 1.0490x over previous
//
#include <hip/hip_runtime.h>
#include <math.h>

#define BN_EPS 1e-5f

typedef __attribute__((ext_vector_type(8))) short bf16x8;
typedef __attribute__((ext_vector_type(4))) float f32x4;

__device__ inline unsigned f2bf(float f) {
  union { float f; unsigned u; } v; v.f = f;
  unsigned r = v.u + 0x7FFF + ((v.u >> 16) & 1);   // round-nearest-even
  return r >> 16;
}

// add-only bf16x8 unpack-accumulate (norm folded into features)
__device__ inline void acc8n(float* a, uint4 v) {
  a[0] += __uint_as_float(v.x << 16);
  a[1] += __uint_as_float(v.x & 0xffff0000u);
  a[2] += __uint_as_float(v.y << 16);
  a[3] += __uint_as_float(v.y & 0xffff0000u);
  a[4] += __uint_as_float(v.z << 16);
  a[5] += __uint_as_float(v.z & 0xffff0000u);
  a[6] += __uint_as_float(v.w << 16);
  a[7] += __uint_as_float(v.w & 0xffff0000u);
}

__device__ inline void acc4n(float* a, uint2 v) {
  a[0] += __uint_as_float(v.x << 16);
  a[1] += __uint_as_float(v.x & 0xffff0000u);
  a[2] += __uint_as_float(v.y << 16);
  a[3] += __uint_as_float(v.y & 0xffff0000u);
}

// ---------------- CSR build ----------------

__global__ void k_count(const int* __restrict__ dst, int* __restrict__ deg,
                        int* __restrict__ posw, int E) {
  int e = blockIdx.x * blockDim.x + threadIdx.x;
  if (e < E) posw[e] = atomicAdd(&deg[dst[e]], 1);
}

__global__ void k_scan1(const int* __restrict__ deg, int* __restrict__ rowstart,
                        int* __restrict__ chunksum, int n) {
  __shared__ int s[1024];
  int i = blockIdx.x * 1024 + threadIdx.x;
  int v = (i < n) ? deg[i] : 0;
  s[threadIdx.x] = v;
  __syncthreads();
  for (int off = 1; off < 1024; off <<= 1) {
    int t = (threadIdx.x >= off) ? s[threadIdx.x - off] : 0;
    __syncthreads();
    s[threadIdx.x] += t;
    __syncthreads();
  }
  if (i < n) rowstart[i] = s[threadIdx.x] - v;   // exclusive within chunk
  if (threadIdx.x == 1023) chunksum[blockIdx.x] = s[1023];
}

// scan3 with scan2 folded in: each block redundantly prefixes the <=48 chunk sums
__global__ void k_scan3(int* __restrict__ rowstart, const int* __restrict__ chunksum,
                        const int* __restrict__ deg, float* __restrict__ dis,
                        int n, int E) {
  int pre = 0;
  for (int c = 0; c < (int)blockIdx.x; c++) pre += chunksum[c];
  int i = blockIdx.x * 1024 + threadIdx.x;
  if (i < n) {
    rowstart[i] += pre;
    dis[i] = rsqrtf((float)(deg[i] + 1));   // +1 self loop
  }
  if (i == 0) rowstart[n] = E;
}

// ------ prep: deg zero + BN fold (incl. bias) + weight transpose/bf16 + b3 pad --------
// 128 blocks x 128 threads. Stream order makes the deg zero visible to k_count.

__global__ void k_prep(const float* __restrict__ W1, const float* __restrict__ W2,
                       const float* __restrict__ W3,
                       const float* __restrict__ g1, const float* __restrict__ be1,
                       const float* __restrict__ m1, const float* __restrict__ v1,
                       const float* __restrict__ g2, const float* __restrict__ be2,
                       const float* __restrict__ m2, const float* __restrict__ v2,
                       const float* __restrict__ b1, const float* __restrict__ b2,
                       const float* __restrict__ b3,
                       ushort* __restrict__ WT1, ushort* __restrict__ WT2,
                       ushort* __restrict__ WT3,
                       float* __restrict__ sc1, float* __restrict__ sh1,
                       float* __restrict__ sc2, float* __restrict__ sh2,
                       float* __restrict__ b3pad,
                       uint4* __restrict__ degz, int deg16) {
  int k = blockIdx.x;      // 128
  int n = threadIdx.x;     // 128
  int tid = k * 128 + n;
  if (tid < deg16) degz[tid] = make_uint4(0, 0, 0, 0);
  WT1[n * 128 + k] = (ushort)f2bf(W1[k * 128 + n]);
  WT2[n * 128 + k] = (ushort)f2bf(W2[k * 128 + n]);
  WT3[n * 128 + k] = (n < 40) ? (ushort)f2bf(W3[k * 40 + n]) : (ushort)0;
  if (k == 0) {
    float s1 = g1[n] * rsqrtf(v1[n] + BN_EPS);
    sc1[n] = s1; sh1[n] = be1[n] + (b1[n] - m1[n]) * s1;    // bias folded in
    float s2 = g2[n] * rsqrtf(v2[n] + BN_EPS);
    sc2[n] = s2; sh2[n] = be2[n] + (b2[n] - m2[n]) * s2;
  } else if (k == 1 && n < 64) {
    b3pad[n] = (n < 40) ? b3[n] : 0.f;
  }
}

// ---- MFMA GEMM: C[r][c] = dis[r] * (A[r][:] @ W[:][c]), bf16 out.  Optional fused
// ---- CSR-fill role for blocks >= gemmBlocks (layer 1: fill hides under GEMM).

template <bool F32A, bool FILL>
__global__ __launch_bounds__(256) void k_gemm_bf16(const void* __restrict__ Ap,
                                                   const ushort* __restrict__ WT,
                                                   ushort* __restrict__ C,
                                                   const float* __restrict__ dis,
                                                   int nrows, int NC, int gemmBlocks,
                                                   const int* __restrict__ ei,
                                                   const int* __restrict__ rowstart,
                                                   const int* __restrict__ posw,
                                                   unsigned* __restrict__ slot, int E) {
  if (FILL && (int)blockIdx.x >= gemmBlocks) {
    int e = ((int)blockIdx.x - gemmBlocks) * 256 + threadIdx.x;
    if (e < E) slot[rowstart[ei[E + e]] + posw[e]] = (unsigned)ei[e];
    return;
  }
  __shared__ ushort As[128][80];
  __shared__ ushort Bs[128][80];
  const int tid  = threadIdx.x;
  const int lane = tid & 63;
  const int wid  = tid >> 6;
  const int wr   = wid >> 1, wc = wid & 1;
  const int row0 = blockIdx.x * 128;
  f32x4 acc[4][4] = {};

  const int mrow = lane & 15;
  const int kg   = (lane >> 4) * 8;

  for (int k0 = 0; k0 < 128; k0 += 64) {
    __syncthreads();
    for (int i = tid; i < 1024; i += 256) {        // A tile: 128 rows x 64 bf16
      int r = i >> 3, c = (i & 7) * 8;
      uint4 w = make_uint4(0, 0, 0, 0);
      if (row0 + r < nrows) {
        if (F32A) {
          const float* A = (const float*)Ap;
          float4 v0 = *(const float4*)(A + (size_t)(row0 + r) * 128 + k0 + c);
          float4 v1 = *(const float4*)(A + (size_t)(row0 + r) * 128 + k0 + c + 4);
          w.x = f2bf(v0.x) | (f2bf(v0.y) << 16);
          w.y = f2bf(v0.z) | (f2bf(v0.w) << 16);
          w.z = f2bf(v1.x) | (f2bf(v1.y) << 16);
          w.w = f2bf(v1.z) | (f2bf(v1.w) << 16);
        } else {
          const ushort* A = (const ushort*)Ap;
          w = *(const uint4*)(A + (size_t)(row0 + r) * 128 + k0 + c);
        }
      }
      *(uint4*)(&As[r][c]) = w;
    }
    for (int i = tid; i < 1024; i += 256) {        // B tile: 128 n-rows x 64 bf16 (k)
      int r = i >> 3, c = (i & 7) * 8;
      *(uint4*)(&Bs[r][c]) = *(const uint4*)(WT + r * 128 + k0 + c);
    }
    __syncthreads();

#pragma unroll
    for (int ks = 0; ks < 2; ks++) {
      bf16x8 a[4], b[4];
#pragma unroll
      for (int f = 0; f < 4; f++) {
        a[f] = *(const bf16x8*)(&As[wr * 64 + f * 16 + mrow][ks * 32 + kg]);
        b[f] = *(const bf16x8*)(&Bs[wc * 64 + f * 16 + mrow][ks * 32 + kg]);
      }
#pragma unroll
      for (int fm = 0; fm < 4; fm++)
#pragma unroll
        for (int fn = 0; fn < 4; fn++)
          acc[fm][fn] = __builtin_amdgcn_mfma_f32_16x16x32_bf16(a[fm], b[fn], acc[fm][fn], 0, 0, 0);
    }
  }

  // C/D layout: col = lane&15, row = (lane>>4)*4 + reg
  const int rl = (lane >> 4) * 4;
  const int cl = lane & 15;
#pragma unroll
  for (int fm = 0; fm < 4; fm++) {
#pragma unroll
    for (int r = 0; r < 4; r++) {
      int row = row0 + wr * 64 + fm * 16 + rl + r;
      if (row >= nrows) continue;
      float dn = dis[row];
#pragma unroll
      for (int fn = 0; fn < 4; fn++) {
        int col = wc * 64 + fn * 16 + cl;
        if (col < NC) C[(size_t)row * NC + col] = (ushort)f2bf(acc[fm][fn][r] * dn);
      }
    }
  }
}

// ---- Aggregation (D=128): out = relu(sc*(dis[n]*(Σ h'[src] + h'[n])) + sh), bf16 ------
// Wave = 4 edge-groups x 16 lanes; lane gathers 8 channels (16B). 4-deep gather ILP.

__global__ __launch_bounds__(256) void k_agg128b(const ushort* __restrict__ h,
                          const int* __restrict__ rowstart,
                          const unsigned* __restrict__ slot,
                          const float* __restrict__ dis,
                          const float* __restrict__ bnsc,
                          const float* __restrict__ bnsh,
                          ushort* __restrict__ out, int nnodes) {
  int node = blockIdx.x * 4 + threadIdx.y;
  if (node >= nnodes) return;
  int lane = threadIdx.x;
  int eg = lane >> 4, cl = lane & 15, c0 = cl * 8;
  int s = rowstart[node], e = rowstart[node + 1];
  int deg = e - s;
  unsigned mys = 0;
  if (lane < deg) mys = slot[s + lane];
  float a[8] = {0.f, 0.f, 0.f, 0.f, 0.f, 0.f, 0.f, 0.f};
  int nb = deg < 64 ? deg : 64;
  int i = eg;
  for (; i + 12 < nb; i += 16) {                 // 4 independent gathers in flight
    int s0 = __shfl((int)mys, i);
    int s1 = __shfl((int)mys, i + 4);
    int s2 = __shfl((int)mys, i + 8);
    int s3 = __shfl((int)mys, i + 12);
    uint4 h0 = *(const uint4*)(h + (size_t)s0 * 128 + c0);
    uint4 h1 = *(const uint4*)(h + (size_t)s1 * 128 + c0);
    uint4 h2 = *(const uint4*)(h + (size_t)s2 * 128 + c0);
    uint4 h3 = *(const uint4*)(h + (size_t)s3 * 128 + c0);
    acc8n(a, h0); acc8n(a, h1); acc8n(a, h2); acc8n(a, h3);
  }
  for (; i + 4 < nb; i += 8) {
    int s0 = __shfl((int)mys, i);
    int s1 = __shfl((int)mys, i + 4);
    uint4 h0 = *(const uint4*)(h + (size_t)s0 * 128 + c0);
    uint4 h1 = *(const uint4*)(h + (size_t)s1 * 128 + c0);
    acc8n(a, h0); acc8n(a, h1);
  }
  if (i < nb) {
    int s0 = __shfl((int)mys, i);
    uint4 h0 = *(const uint4*)(h + (size_t)s0 * 128 + c0);
    acc8n(a, h0);
  }
  for (int j = s + 64 + eg; j < e; j += 4) {     // rare tail (deg > 64)
    uint4 h0 = *(const uint4*)(h + (size_t)slot[j] * 128 + c0);
    acc8n(a, h0);
  }
#pragma unroll
  for (int j = 0; j < 8; j++) {
    a[j] += __shfl_xor(a[j], 16);
    a[j] += __shfl_xor(a[j], 32);
  }
  if (eg == 0) {
    uint4 hv = *(const uint4*)(h + (size_t)node * 128 + c0);
    acc8n(a, hv);                                 // self loop
    float dn = dis[node];
    float4 sc0 = *(const float4*)(bnsc + c0), sc1 = *(const float4*)(bnsc + c0 + 4);
    float4 sh0 = *(const float4*)(bnsh + c0), sh1 = *(const float4*)(bnsh + c0 + 4);
    float o0 = fmaxf(fmaf(a[0] * dn, sc0.x, sh0.x), 0.f);
    float o1 = fmaxf(fmaf(a[1] * dn, sc0.y, sh0.y), 0.f);
    float o2 = fmaxf(fmaf(a[2] * dn, sc0.z, sh0.z), 0.f);
    float o3 = fmaxf(fmaf(a[3] * dn, sc0.w, sh0.w), 0.f);
    float o4 = fmaxf(fmaf(a[4] * dn, sc1.x, sh1.x), 0.f);
    float o5 = fmaxf(fmaf(a[5] * dn, sc1.y, sh1.y), 0.f);
    float o6 = fmaxf(fmaf(a[6] * dn, sc1.z, sh1.z), 0.f);
    float o7 = fmaxf(fmaf(a[7] * dn, sc1.w, sh1.w), 0.f);
    uint4 w;
    w.x = f2bf(o0) | (f2bf(o1) << 16);
    w.y = f2bf(o2) | (f2bf(o3) << 16);
    w.z = f2bf(o4) | (f2bf(o5) << 16);
    w.w = f2bf(o6) | (f2bf(o7) << 16);
    *(uint4*)(out + (size_t)node * 128 + c0) = w;
  }
}

// -------- Aggregation (64-padded layer-3) + log_softmax (fp32 out, 40 ch) --------------

__global__ __launch_bounds__(256) void k_agg64_lsm(const ushort* __restrict__ h,
                            const int* __restrict__ rowstart,
                            const unsigned* __restrict__ slot,
                            const float* __restrict__ dis,
                            const float* __restrict__ b3pad,
                            float* __restrict__ out, int nnodes) {
  int node = blockIdx.x * 4 + threadIdx.y;
  if (node >= nnodes) return;
  int lane = threadIdx.x;
  int eg = lane >> 4, cl = lane & 15, c0 = cl * 4;
  int s = rowstart[node], e = rowstart[node + 1];
  int deg = e - s;
  unsigned mys = 0;
  if (lane < deg) mys = slot[s + lane];
  float a[4] = {0.f, 0.f, 0.f, 0.f};
  int nb = deg < 64 ? deg : 64;
  int i = eg;
  for (; i + 12 < nb; i += 16) {
    int s0 = __shfl((int)mys, i);
    int s1 = __shfl((int)mys, i + 4);
    int s2 = __shfl((int)mys, i + 8);
    int s3 = __shfl((int)mys, i + 12);
    uint2 h0 = *(const uint2*)(h + (size_t)s0 * 64 + c0);
    uint2 h1 = *(const uint2*)(h + (size_t)s1 * 64 + c0);
    uint2 h2 = *(const uint2*)(h + (size_t)s2 * 64 + c0);
    uint2 h3 = *(const uint2*)(h + (size_t)s3 * 64 + c0);
    acc4n(a, h0); acc4n(a, h1); acc4n(a, h2); acc4n(a, h3);
  }
  for (; i + 4 < nb; i += 8) {
    int s0 = __shfl((int)mys, i);
    int s1 = __shfl((int)mys, i + 4);
    uint2 h0 = *(const uint2*)(h + (size_t)s0 * 64 + c0);
    uint2 h1 = *(const uint2*)(h + (size_t)s1 * 64 + c0);
    acc4n(a, h0); acc4n(a, h1);
  }
  if (i < nb) {
    int s0 = __shfl((int)mys, i);
    uint2 h0 = *(const uint2*)(h + (size_t)s0 * 64 + c0);
    acc4n(a, h0);
  }
  for (int j = s + 64 + eg; j < e; j += 4) {
    uint2 h0 = *(const uint2*)(h + (size_t)slot[j] * 64 + c0);
    acc4n(a, h0);
  }
#pragma unroll
  for (int j = 0; j < 4; j++) {
    a[j] += __shfl_xor(a[j], 16);
    a[j] += __shfl_xor(a[j], 32);
  }
  // self loop + dis scale + bias (identical across edge groups)
  {
    uint2 hv = *(const uint2*)(h + (size_t)node * 64 + c0);
    acc4n(a, hv);
    float dn = dis[node];
    float4 bb = *(const float4*)(b3pad + c0);
    a[0] = fmaf(a[0], dn, bb.x);
    a[1] = fmaf(a[1], dn, bb.y);
    a[2] = fmaf(a[2], dn, bb.z);
    a[3] = fmaf(a[3], dn, bb.w);
  }
  bool valid = cl < 10;   // channels 4*cl..4*cl+3 < 40
  float m = valid ? fmaxf(fmaxf(a[0], a[1]), fmaxf(a[2], a[3])) : -INFINITY;
#pragma unroll
  for (int off = 1; off < 16; off <<= 1) m = fmaxf(m, __shfl_xor(m, off));
  float ss = valid ? (expf(a[0] - m) + expf(a[1] - m) + expf(a[2] - m) + expf(a[3] - m)) : 0.f;
#pragma unroll
  for (int off = 1; off < 16; off <<= 1) ss += __shfl_xor(ss, off);
  float lse = m + logf(ss);
  if (eg == 0 && valid) {
    *(float4*)(out + (size_t)node * 40 + c0) =
        make_float4(a[0] - lse, a[1] - lse, a[2] - lse, a[3] - lse);
  }
}

// ---------------- launch ----------------

extern "C" void kernel_launch(void* const* d_in, const int* in_sizes, int n_in,
                              void* d_out, int out_size, void* d_ws, size_t ws_size,
                              hipStream_t stream) {
  const float* x   = (const float*)d_in[0];
  const int*   ei  = (const int*)d_in[1];
  const float* W1  = (const float*)d_in[2];
  const float* b1  = (const float*)d_in[3];
  const float* W2  = (const float*)d_in[4];
  const float* b2  = (const float*)d_in[5];
  const float* W3  = (const float*)d_in[6];
  const float* b3  = (const float*)d_in[7];
  const float* g1  = (const float*)d_in[8];
  const float* be1 = (const float*)d_in[9];
  const float* m1  = (const float*)d_in[10];
  const float* v1  = (const float*)d_in[11];
  const float* g2  = (const float*)d_in[12];
  const float* be2 = (const float*)d_in[13];
  const float* m2  = (const float*)d_in[14];
  const float* v2  = (const float*)d_in[15];

  const int N   = in_sizes[0] / 128;
  const int E   = in_sizes[1] / 2;

  float* outp = (float*)d_out;

  char* ws = (char*)d_ws;
  size_t off = 0;
  auto alloc = [&](size_t bytes) -> char* {
    char* p = ws + off;
    off = (off + bytes + 255) & ~(size_t)255;
    return p;
  };
  const int deg16 = (N + 3) / 4;
  int*      deg      = (int*)alloc((size_t)deg16 * 16);
  int*      posw     = (int*)alloc((size_t)E * 4);
  int*      rowstart = (int*)alloc((size_t)(N + 1) * 4);
  int*      chunksum = (int*)alloc(256 * 4);
  float*    dis      = (float*)alloc((size_t)N * 4);
  unsigned* slot     = (unsigned*)alloc((size_t)E * 4);
  float*    sc1      = (float*)alloc(128 * 4);
  float*    sh1      = (float*)alloc(128 * 4);
  float*    sc2      = (float*)alloc(128 * 4);
  float*    sh2      = (float*)alloc(128 * 4);
  float*    b3pad    = (float*)alloc(64 * 4);
  ushort*   WT1      = (ushort*)alloc(128 * 128 * 2);
  ushort*   WT2      = (ushort*)alloc(128 * 128 * 2);
  ushort*   WT3      = (ushort*)alloc(128 * 128 * 2);
  ushort*   bufA     = (ushort*)alloc((size_t)N * 128 * 2);
  ushort*   bufB     = (ushort*)alloc((size_t)N * 128 * 2);
  ushort*   bufC     = (ushort*)alloc((size_t)N * 64 * 2);
  (void)ws_size;

  const int T = 256;
  const int chunks = (N + 1023) / 1024;

  // prep (also zeroes deg) -> count -> scan1 -> scan3(with scan2 folded)
  k_prep<<<128, 128, 0, stream>>>(W1, W2, W3, g1, be1, m1, v1, g2, be2, m2, v2,
                                  b1, b2, b3, WT1, WT2, WT3, sc1, sh1, sc2, sh2, b3pad,
                                  (uint4*)deg, deg16);
  k_count<<<(E + T - 1) / T, T, 0, stream>>>(ei + E, deg, posw, E);
  k_scan1<<<chunks, 1024, 0, stream>>>(deg, rowstart, chunksum, N);
  k_scan3<<<chunks, 1024, 0, stream>>>(rowstart, chunksum, deg, dis, N, E);

  dim3 aggGrid((N + 3) / 4), aggBlk(64, 4);
  const int gBlocks = (N + 127) / 128;
  const int fBlocks = (E + 255) / 256;

  // Layer 1: GEMM (fp32 in, dis-scaled bf16 out) with CSR fill fused in extra blocks
  k_gemm_bf16<true, true><<<gBlocks + fBlocks, 256, 0, stream>>>(
      x, WT1, bufB, dis, N, 128, gBlocks, ei, rowstart, posw, slot, E);
  k_agg128b<<<aggGrid, aggBlk, 0, stream>>>(bufB, rowstart, slot, dis, sc1, sh1, bufA, N);

  // Layer 2
  k_gemm_bf16<false, false><<<gBlocks, 256, 0, stream>>>(
      bufA, WT2, bufB, dis, N, 128, gBlocks, nullptr, nullptr, nullptr, nullptr, 0);
  k_agg128b<<<aggGrid, aggBlk, 0, stream>>>(bufB, rowstart, slot, dis, sc2, sh2, bufA, N);

  // Layer 3 (64-padded) + log_softmax
  k_gemm_bf16<false, false><<<gBlocks, 256, 0, stream>>>(
      bufA, WT3, bufC, dis, N, 64, gBlocks, nullptr, nullptr, nullptr, nullptr, 0);
  k_agg64_lsm<<<aggGrid, aggBlk, 0, stream>>>(bufC, rowstart, slot, dis, b3pad, outp, N);
}